// Round 1
// baseline (159.526 us; speedup 1.0000x reference)
//
#include <hip/hip_runtime.h>
#include <hip/hip_bf16.h>

// B=4 S=1024 D=1024 H=16 DH=64 -> flat M=4096, attention view [64][1024][64]

using u16 = unsigned short;
typedef __attribute__((ext_vector_type(8))) short bf16x8;
typedef __attribute__((ext_vector_type(4))) float f32x4;
typedef __attribute__((ext_vector_type(4))) u16  u16x4;
typedef __attribute__((ext_vector_type(8))) u16  u16x8;

#define AS1C(p) ((const __attribute__((address_space(1))) void*)(p))
#define AS3(p)  ((__attribute__((address_space(3))) void*)(p))

__device__ __forceinline__ u16 f2bf(float f) {
  union { float f; unsigned u; } v; v.f = f;
  unsigned u = v.u;
  return (u16)((u + 0x7fffu + ((u >> 16) & 1u)) >> 16);  // RNE
}

__device__ __forceinline__ f32x4 mfma16(bf16x8 a, bf16x8 b, f32x4 c) {
  return __builtin_amdgcn_mfma_f32_16x16x32_bf16(a, b, c, 0, 0, 0);
}

// ---------------- prep: fp32->bf16 for x and W's, concat biases ----------------
// chunks of 4 floats: [0,1M) x ; [1M,2M) Wq/Wk/Wv/Wo ; [2M, 2M+768) bq|bk|bv copy
__global__ __launch_bounds__(256) void prep_kernel(
    const float* __restrict__ x,
    const float* __restrict__ wq, const float* __restrict__ wk,
    const float* __restrict__ wv, const float* __restrict__ wo,
    const float* __restrict__ bq, const float* __restrict__ bk, const float* __restrict__ bv,
    u16* __restrict__ xb, u16* __restrict__ wb, float* __restrict__ bc)
{
  int ch = blockIdx.x * 256 + threadIdx.x;
  if (ch < 2097152) {
    const float* src; u16* dst;
    if (ch < 1048576) { src = x + ch * 4; dst = xb + ch * 4; }
    else {
      int c2 = ch - 1048576;
      int wsel = c2 >> 18;            // 262144 float4-chunks per 1M-elem W
      int off  = c2 & 262143;
      const float* wsrc[4] = { wq, wk, wv, wo };
      src = wsrc[wsel] + off * 4;
      dst = wb + wsel * 1048576 + off * 4;
    }
    f32x4 v = *(const f32x4*)src;
    u16x4 o;
    o[0] = f2bf(v[0]); o[1] = f2bf(v[1]); o[2] = f2bf(v[2]); o[3] = f2bf(v[3]);
    *(u16x4*)dst = o;
  } else {
    int c3 = ch - 2097152;            // < 768
    int bsel = c3 >> 8, off = c3 & 255;
    const float* bsrc[3] = { bq, bk, bv };
    f32x4 v = *(const f32x4*)(bsrc[bsel] + off * 4);
    *(f32x4*)(bc + bsel * 1024 + off * 4) = v;
  }
}

// ---------------- GEMM C = A * W^T (+bias [, *0.125 | +residual]) ----------------
// A [M][1024] bf16, Bw [N][1024] bf16 (K-major both). 128x128 tile, BK=32, 4 waves.
// MODE 0: out bf16 -> qkv[3][4096][1024], bias=concat[3072], Q cols (<1024) scaled 1/8.
// MODE 1: out f32 = acc + bias + residual(x).
template <int MODE>
__global__ __launch_bounds__(256) void gemm_bt(
    const u16* __restrict__ A, const u16* __restrict__ Bw,
    const float* __restrict__ bias, const float* __restrict__ resid,
    u16* __restrict__ outb, float* __restrict__ outf)
{
  __shared__ u16 As[128 * 32];
  __shared__ u16 Bs[128 * 32];
  const int K = 1024;
  int bm = blockIdx.x, bn = blockIdx.y;
  int tid = threadIdx.x;
  int wid = tid >> 6, lane = tid & 63;
  int g = lane >> 4, lr = lane & 15;
  int wr = wid >> 1, wc = wid & 1;   // 2x2 waves, each 64x64

  f32x4 acc[4][4] = {};

  for (int kt = 0; kt < K / 32; ++kt) {
    // stage A,B tiles: 8KB each = 8 wave-chunks of 1KB (lane*16B linear dest)
#pragma unroll
    for (int it = 0; it < 2; ++it) {
      int ch = (it * 4 + wid) * 64 + lane;   // [0,512)
      int row = ch >> 2, kp = ch & 3;
      const u16* ga = A  + (size_t)(bm * 128 + row) * K + kt * 32 + kp * 8;
      const u16* gb = Bw + (size_t)(bn * 128 + row) * K + kt * 32 + kp * 8;
      __builtin_amdgcn_global_load_lds(AS1C(ga), AS3(&As[(it * 4 + wid) * 512]), 16, 0, 0);
      __builtin_amdgcn_global_load_lds(AS1C(gb), AS3(&Bs[(it * 4 + wid) * 512]), 16, 0, 0);
    }
    __syncthreads();   // drains vmcnt before barrier

    bf16x8 af[4], bf[4];
#pragma unroll
    for (int m = 0; m < 4; ++m)
      af[m] = *(const bf16x8*)&As[(wr * 64 + m * 16 + lr) * 32 + 8 * g];
#pragma unroll
    for (int n = 0; n < 4; ++n)
      bf[n] = *(const bf16x8*)&Bs[(wc * 64 + n * 16 + lr) * 32 + 8 * g];
#pragma unroll
    for (int m = 0; m < 4; ++m)
#pragma unroll
      for (int n = 0; n < 4; ++n)
        acc[m][n] = mfma16(af[m], bf[n], acc[m][n]);
    __syncthreads();   // WAR: everyone done reading before next stage
  }

  // epilogue: D layout col=lane&15, row=(lane>>4)*4+i
#pragma unroll
  for (int m = 0; m < 4; ++m) {
    int row0 = bm * 128 + wr * 64 + m * 16 + 4 * g;
#pragma unroll
    for (int n = 0; n < 4; ++n) {
      int col = bn * 128 + wc * 64 + n * 16 + lr;
#pragma unroll
      for (int i = 0; i < 4; ++i) {
        float v = acc[m][n][i];
        if (MODE == 0) {
          v += bias[col];
          if (col < 1024) v *= 0.125f;             // fold attention scale into Q
          int sel = col >> 10;
          outb[(size_t)sel * 4194304 + (size_t)(row0 + i) * 1024 + (col & 1023)] = f2bf(v);
        } else {
          size_t idx = (size_t)(row0 + i) * 1024 + col;
          outf[idx] = v + bias[col] + resid[idx];
        }
      }
    }
  }
}

// ---------------- flash attention over [64][1024][64], KV-tile = 64 ----------------
__global__ __launch_bounds__(256) void attn_kernel(
    const u16* __restrict__ Qb, const u16* __restrict__ Kb,
    const u16* __restrict__ Vb, u16* __restrict__ Ob)
{
  __shared__ u16 Ks[64 * 64];       // [kc][d] bf16, XOR-swizzled 16B chunks
  __shared__ u16 Vt[64 * 72];       // [d][kc] transposed, pad 72
  __shared__ u16 Ps[4][16 * 72];    // per-wave P tile [16 q][64 k], pad 72

  int bIdx = blockIdx.x;
  int bh = bIdx >> 4, qt = bIdx & 15;
  int tid = threadIdx.x, wid = tid >> 6, lane = tid & 63;
  int g = lane >> 4, lr = lane & 15;

  const u16* Qp = Qb + (size_t)bh * 65536;
  const u16* Kp = Kb + (size_t)bh * 65536;
  const u16* Vp = Vb + (size_t)bh * 65536;

  // Q fragments (rows qt*64 + wid*16 + lr), held in registers, read once
  bf16x8 qf[2];
#pragma unroll
  for (int f = 0; f < 2; ++f)
    qf[f] = *(const bf16x8*)&Qp[(size_t)(qt * 64 + wid * 16 + lr) * 64 + f * 32 + 8 * g];

  f32x4 oacc[4] = {};
  float mrow[4], lrowv[4];
#pragma unroll
  for (int i = 0; i < 4; ++i) { mrow[i] = -1e30f; lrowv[i] = 0.f; }

  for (int kt = 0; kt < 16; ++kt) {
    // --- stage K via global_load_lds, source pre-swizzled: slot(kc,sch) <- dchunk sch^(kc&7)
#pragma unroll
    for (int it = 0; it < 2; ++it) {
      int ch = (it * 4 + wid) * 64 + lane;      // [0,512) 16B chunks
      int kc = ch >> 3, sch = ch & 7;
      int sdch = sch ^ (kc & 7);
      const u16* gk = Kp + (size_t)(kt * 64 + kc) * 64 + sdch * 8;
      __builtin_amdgcn_global_load_lds(AS1C(gk), AS3(&Ks[(it * 4 + wid) * 512]), 16, 0, 0);
    }
    // --- stage V transposed: Vt[d][kc]
#pragma unroll
    for (int i2 = 0; i2 < 2; ++i2) {
      int ch2 = tid * 2 + i2;                   // [0,512)
      int kc = ch2 >> 3, dch = ch2 & 7;
      u16x8 v8 = *(const u16x8*)&Vp[(size_t)(kt * 64 + kc) * 64 + dch * 8];
#pragma unroll
      for (int j = 0; j < 8; ++j)
        Vt[(dch * 8 + j) * 72 + kc] = v8[j];
    }
    __syncthreads();

    // --- S = Q K^T (Q pre-scaled by 1/8). s[n][i] = S[4g+i][n*16+lr]
    f32x4 s[4];
#pragma unroll
    for (int n = 0; n < 4; ++n) {
      f32x4 z = { 0.f, 0.f, 0.f, 0.f };
#pragma unroll
      for (int f = 0; f < 2; ++f) {
        int kcrow = n * 16 + lr;
        bf16x8 kb = *(const bf16x8*)&Ks[kcrow * 64 + (((f * 4 + g) ^ (kcrow & 7)) * 8)];
        z = mfma16(qf[f], kb, z);
      }
      s[n] = z;
    }

    // --- online softmax (row = 4g+i spread over 16 lr-lanes)
    float corr[4], pvv[4][4];
#pragma unroll
    for (int i = 0; i < 4; ++i) {
      float tm = fmaxf(fmaxf(s[0][i], s[1][i]), fmaxf(s[2][i], s[3][i]));
#pragma unroll
      for (int ms = 1; ms < 16; ms <<= 1) tm = fmaxf(tm, __shfl_xor(tm, ms));
      float mn = fmaxf(mrow[i], tm);
      corr[i] = __expf(mrow[i] - mn);
      float rs = 0.f;
#pragma unroll
      for (int n = 0; n < 4; ++n) {
        float p = __expf(s[n][i] - mn);
        pvv[n][i] = p; rs += p;
      }
#pragma unroll
      for (int ms = 1; ms < 16; ms <<= 1) rs += __shfl_xor(rs, ms);
      lrowv[i] = lrowv[i] * corr[i] + rs;
      mrow[i] = mn;
    }
#pragma unroll
    for (int nd = 0; nd < 4; ++nd) {
      f32x4 o = oacc[nd];
      o[0] *= corr[0]; o[1] *= corr[1]; o[2] *= corr[2]; o[3] *= corr[3];
      oacc[nd] = o;
    }
    // --- P -> LDS (wave-local), then PV
#pragma unroll
    for (int n = 0; n < 4; ++n)
#pragma unroll
      for (int i = 0; i < 4; ++i)
        Ps[wid][(4 * g + i) * 72 + n * 16 + lr] = f2bf(pvv[n][i]);
    asm volatile("s_waitcnt lgkmcnt(0)" ::: "memory");

#pragma unroll
    for (int f = 0; f < 2; ++f) {
      bf16x8 pa = *(const bf16x8*)&Ps[wid][lr * 72 + f * 32 + 8 * g];
#pragma unroll
      for (int nd = 0; nd < 4; ++nd) {
        bf16x8 vb = *(const bf16x8*)&Vt[(nd * 16 + lr) * 72 + f * 32 + 8 * g];
        oacc[nd] = mfma16(pa, vb, oacc[nd]);
      }
    }
    __syncthreads();   // protect Ks/Vt before next stage
  }

  // epilogue: ctx = oacc / l
  u16* Op = Ob + (size_t)bh * 65536 + (size_t)(qt * 64 + wid * 16) * 64;
#pragma unroll
  for (int nd = 0; nd < 4; ++nd)
#pragma unroll
    for (int i = 0; i < 4; ++i)
      Op[(4 * g + i) * 64 + nd * 16 + lr] = f2bf(oacc[nd][i] / lrowv[i]);
}

// ---------------- LayerNorm in-place over rows of out [4096][1024] ----------------
__global__ __launch_bounds__(256) void ln_kernel(
    float* __restrict__ out, const float* __restrict__ gamma, const float* __restrict__ beta)
{
  int row = blockIdx.x, tid = threadIdx.x;
  int lane = tid & 63, wid = tid >> 6;
  f32x4 v = *(const f32x4*)&out[(size_t)row * 1024 + tid * 4];
  float s = v[0] + v[1] + v[2] + v[3];
  float q = v[0] * v[0] + v[1] * v[1] + v[2] * v[2] + v[3] * v[3];
#pragma unroll
  for (int ms = 1; ms < 64; ms <<= 1) { s += __shfl_xor(s, ms); q += __shfl_xor(q, ms); }
  __shared__ float red[8];
  if (lane == 0) { red[wid] = s; red[wid + 4] = q; }
  __syncthreads();
  s = red[0] + red[1] + red[2] + red[3];
  q = red[4] + red[5] + red[6] + red[7];
  float mu = s * (1.f / 1024.f);
  float var = q * (1.f / 1024.f) - mu * mu;
  float inv = rsqrtf(var + 1e-5f);
  f32x4 g4 = *(const f32x4*)&gamma[tid * 4];
  f32x4 b4 = *(const f32x4*)&beta[tid * 4];
  f32x4 o;
#pragma unroll
  for (int j = 0; j < 4; ++j) o[j] = (v[j] - mu) * inv * g4[j] + b4[j];
  *(f32x4*)&out[(size_t)row * 1024 + tid * 4] = o;
}

// ---------------- launch ----------------
extern "C" void kernel_launch(void* const* d_in, const int* in_sizes, int n_in,
                              void* d_out, int out_size, void* d_ws, size_t ws_size,
                              hipStream_t stream) {
  const float* x     = (const float*)d_in[0];
  const float* Wq    = (const float*)d_in[1];
  const float* bq    = (const float*)d_in[2];
  const float* Wk    = (const float*)d_in[3];
  const float* bk    = (const float*)d_in[4];
  const float* Wv    = (const float*)d_in[5];
  const float* bv    = (const float*)d_in[6];
  const float* Wo    = (const float*)d_in[7];
  const float* bo    = (const float*)d_in[8];
  const float* gamma = (const float*)d_in[9];
  const float* beta  = (const float*)d_in[10];
  float* out = (float*)d_out;

  char* ws = (char*)d_ws;
  u16*   xb  = (u16*)ws;                                   // 8MB  [4096][1024] bf16 (reused as ctx)
  u16*   wb  = (u16*)(ws + (8u << 20));                    // 8MB  Wq|Wk|Wv|Wo bf16
  float* bc  = (float*)(ws + (16u << 20));                 // 12KB bq|bk|bv
  u16*   qkv = (u16*)(ws + (16u << 20) + 16384);           // 24MB [3][4096][1024] bf16
  u16*   ctx = xb;                                         // overlay: xb dead after QKV GEMM

  prep_kernel<<<8195, 256, 0, stream>>>(x, Wq, Wk, Wv, Wo, bq, bk, bv, xb, wb, bc);

  dim3 g0(32, 24);
  gemm_bt<0><<<g0, 256, 0, stream>>>(xb, wb, bc, nullptr, qkv, nullptr);

  attn_kernel<<<1024, 256, 0, stream>>>(qkv, qkv + 4194304, qkv + 8388608, ctx);

  dim3 g1(32, 8);
  gemm_bt<1><<<g1, 256, 0, stream>>>(ctx, wb + 3 * 1048576, bo, x, nullptr, out);

  ln_kernel<<<4096, 256, 0, stream>>>(out, gamma, beta);
}

// Round 2
// 150.353 us; speedup vs baseline: 1.0610x; 1.0610x over previous
//
#include <hip/hip_runtime.h>
#include <hip/hip_bf16.h>

// B=4 S=1024 D=1024 H=16 DH=64 -> flat M=4096, attention raw view [64][1024][64]

using u16 = unsigned short;
typedef __attribute__((ext_vector_type(8))) short bf16x8;
typedef __attribute__((ext_vector_type(4))) float f32x4;
typedef __attribute__((ext_vector_type(4))) u16  u16x4;
typedef __attribute__((ext_vector_type(8))) u16  u16x8;

#define AS1C(p) ((const __attribute__((address_space(1))) void*)(p))
#define AS3(p)  ((__attribute__((address_space(3))) void*)(p))

__device__ __forceinline__ u16 f2bf(float f) {
  union { float f; unsigned u; } v; v.f = f;
  unsigned u = v.u;
  return (u16)((u + 0x7fffu + ((u >> 16) & 1u)) >> 16);  // RNE
}

__device__ __forceinline__ f32x4 mfma16(bf16x8 a, bf16x8 b, f32x4 c) {
  return __builtin_amdgcn_mfma_f32_16x16x32_bf16(a, b, c, 0, 0, 0);
}

// ---------------- prep: fp32->bf16 for x and W's, concat biases ----------------
__global__ __launch_bounds__(256) void prep_kernel(
    const float* __restrict__ x,
    const float* __restrict__ wq, const float* __restrict__ wk,
    const float* __restrict__ wv, const float* __restrict__ wo,
    const float* __restrict__ bq, const float* __restrict__ bk, const float* __restrict__ bv,
    u16* __restrict__ xb, u16* __restrict__ wb, float* __restrict__ bc)
{
  int ch = blockIdx.x * 256 + threadIdx.x;
  if (ch < 2097152) {
    const float* src; u16* dst;
    if (ch < 1048576) { src = x + ch * 4; dst = xb + ch * 4; }
    else {
      int c2 = ch - 1048576;
      int wsel = c2 >> 18;
      int off  = c2 & 262143;
      const float* wsrc[4] = { wq, wk, wv, wo };
      src = wsrc[wsel] + off * 4;
      dst = wb + wsel * 1048576 + off * 4;
    }
    f32x4 v = *(const f32x4*)src;
    u16x4 o;
    o[0] = f2bf(v[0]); o[1] = f2bf(v[1]); o[2] = f2bf(v[2]); o[3] = f2bf(v[3]);
    *(u16x4*)dst = o;
  } else {
    int c3 = ch - 2097152;            // < 768
    int bsel = c3 >> 8, off = c3 & 255;
    const float* bsrc[3] = { bq, bk, bv };
    f32x4 v = *(const f32x4*)(bsrc[bsel] + off * 4);
    *(f32x4*)(bc + bsel * 1024 + off * 4) = v;
  }
}

// ---------------- GEMM C = A * W^T, 128x128 tile, BK=32, 4 waves, dbuf 1-barrier ----------------
// MODE 0: out -> Q[4096][1024]*0.125 | K[4096][1024] | V^T[64bh][64dh][1024k], all bf16.
// MODE 1: out f32 = acc + bias + residual(x).
template <int MODE>
__global__ __launch_bounds__(256) void gemm_bt(
    const u16* __restrict__ A, const u16* __restrict__ Bw,
    const float* __restrict__ bias, const float* __restrict__ resid,
    u16* __restrict__ outb, float* __restrict__ outf)
{
  __shared__ u16 As[2][4096];
  __shared__ u16 Bs[2][4096];
  const int K = 1024;
  int bm = blockIdx.x, bn = blockIdx.y;
  int tid = threadIdx.x;
  int wid = tid >> 6, lane = tid & 63;
  int g = lane >> 4, lr = lane & 15;
  int wr = wid >> 1, wc = wid & 1;   // 2x2 waves, each 64x64

  f32x4 acc[4][4] = {};

  // staging: 512 16B-chunks per tile per operand; lane-linear LDS dest
  int sch  = (tid >> 6) * 64 + (tid & 63);      // == tid
  int srow = tid >> 2, skp = tid & 3;
  const u16* gaBase = A  + (size_t)(bm * 128 + srow) * K + skp * 8;
  const u16* gbBase = Bw + (size_t)(bn * 128 + srow) * K + skp * 8;
  int srow2 = 64 + srow;
  const u16* gaBase2 = A  + (size_t)(bm * 128 + srow2) * K + skp * 8;
  const u16* gbBase2 = Bw + (size_t)(bn * 128 + srow2) * K + skp * 8;

#define STAGE_GEMM(b, kt) do { \
    __builtin_amdgcn_global_load_lds(AS1C(gaBase  + (kt) * 32), AS3(&As[b][tid * 8]),        16, 0, 0); \
    __builtin_amdgcn_global_load_lds(AS1C(gbBase  + (kt) * 32), AS3(&Bs[b][tid * 8]),        16, 0, 0); \
    __builtin_amdgcn_global_load_lds(AS1C(gaBase2 + (kt) * 32), AS3(&As[b][2048 + tid * 8]), 16, 0, 0); \
    __builtin_amdgcn_global_load_lds(AS1C(gbBase2 + (kt) * 32), AS3(&Bs[b][2048 + tid * 8]), 16, 0, 0); \
  } while (0)

  STAGE_GEMM(0, 0);
  __syncthreads();
  int cur = 0;

  for (int kt = 0; kt < K / 32; ++kt) {
    if (kt + 1 < K / 32) STAGE_GEMM(cur ^ 1, kt + 1);

    bf16x8 af[4], bfr[4];
#pragma unroll
    for (int m = 0; m < 4; ++m)
      af[m] = *(const bf16x8*)&As[cur][(wr * 64 + m * 16 + lr) * 32 + 8 * g];
#pragma unroll
    for (int n = 0; n < 4; ++n)
      bfr[n] = *(const bf16x8*)&Bs[cur][(wc * 64 + n * 16 + lr) * 32 + 8 * g];
#pragma unroll
    for (int m = 0; m < 4; ++m)
#pragma unroll
      for (int n = 0; n < 4; ++n)
        acc[m][n] = mfma16(af[m], bfr[n], acc[m][n]);
    __syncthreads();   // drains vmcnt(0): next tile staged; lgkm: reads done -> safe overwrite
    cur ^= 1;
  }

  // epilogue: D layout col=lane&15, row=(lane>>4)*4+i
#pragma unroll
  for (int m = 0; m < 4; ++m) {
    int row0 = bm * 128 + wr * 64 + m * 16 + 4 * g;
#pragma unroll
    for (int n = 0; n < 4; ++n) {
      int col = bn * 128 + wc * 64 + n * 16 + lr;
#pragma unroll
      for (int i = 0; i < 4; ++i) {
        float v = acc[m][n][i];
        if (MODE == 0) {
          v += bias[col];
          int r = row0 + i;
          if (col < 1024) {
            outb[(size_t)r * 1024 + col] = f2bf(v * 0.125f);               // Q (scale folded)
          } else if (col < 2048) {
            outb[4194304 + (size_t)r * 1024 + (col - 1024)] = f2bf(v);     // K
          } else {
            int c = col - 2048;
            // V^T[bh=r>>6][dh=c&63][k=(r&63)*16+(c>>6)]
            outb[8388608 + (size_t)(r >> 6) * 65536 + (size_t)(c & 63) * 1024
                 + (r & 63) * 16 + (c >> 6)] = f2bf(v);
          }
        } else {
          size_t idx = (size_t)(row0 + i) * 1024 + col;
          outf[idx] = v + bias[col] + resid[idx];
        }
      }
    }
  }
}

// ---------------- flash attention: raw view [64][1024][64], KV-tile 64, 8 waves ----------------
// block = 128 q-rows (wave w owns 16), dbuf K/V^T staged via global_load_lds (swizzled src)
__global__ __launch_bounds__(512) void attn_kernel(
    const u16* __restrict__ Qb, const u16* __restrict__ Kb,
    const u16* __restrict__ Vtb, u16* __restrict__ Ob)
{
  __shared__ u16 Ks[2][64 * 64];    // [kc][d], chunk-swizzled: LDS[r][c] = glob chunk c^(r&7)
  __shared__ u16 Vts[2][64 * 64];   // [dh][k], same swizzle
  __shared__ u16 Ps[8][16 * 72];    // per-wave P [16 q][64 k], pad 72

  int blk = blockIdx.x;
  int bh = blk & 63, qt = blk >> 6;          // same-head blocks share XCD L2
  int tid = threadIdx.x, wid = tid >> 6, lane = tid & 63;
  int g = lane >> 4, lr = lane & 15;

  const u16* Qp = Qb  + (size_t)bh * 65536;
  const u16* Kp = Kb  + (size_t)bh * 65536;
  const u16* Vp = Vtb + (size_t)bh * 65536;

  // Q fragments: rows qt*128 + wid*16 + lr
  bf16x8 qf[2];
#pragma unroll
  for (int f = 0; f < 2; ++f)
    qf[f] = *(const bf16x8*)&Qp[(size_t)(qt * 128 + wid * 16 + lr) * 64 + f * 32 + 8 * g];

  f32x4 oacc[4] = {};
  float mrow[4], lrowv[4];
#pragma unroll
  for (int i = 0; i < 4; ++i) { mrow[i] = -1e30f; lrowv[i] = 0.f; }

  // staging addresses (512 chunks of 16B per buffer, one instr per thread)
  int kc  = tid >> 3, scc = tid & 7;
  const u16* gkBase = Kp + (size_t)kc * 64 + (size_t)(scc ^ (kc & 7)) * 8;   // + kt*64*64
  const u16* gvBase = Vp + (size_t)kc * 1024 + (size_t)(scc ^ (kc & 7)) * 8; // row=dh, + kt*64

#define STAGE_ATTN(b, kt) do { \
    __builtin_amdgcn_global_load_lds(AS1C(gkBase + (size_t)(kt) * 4096), AS3(&Ks[b][tid * 8]),  16, 0, 0); \
    __builtin_amdgcn_global_load_lds(AS1C(gvBase + (kt) * 64),           AS3(&Vts[b][tid * 8]), 16, 0, 0); \
  } while (0)

  STAGE_ATTN(0, 0);
  __syncthreads();
  int cur = 0;

  for (int kt = 0; kt < 16; ++kt) {
    if (kt + 1 < 16) STAGE_ATTN(cur ^ 1, kt + 1);

    // --- S = Q K^T (Q pre-scaled). s[n][i] = S[4g+i][n*16+lr]
    f32x4 s[4];
#pragma unroll
    for (int n = 0; n < 4; ++n) {
      f32x4 z = { 0.f, 0.f, 0.f, 0.f };
      int kr = n * 16 + lr;
#pragma unroll
      for (int f = 0; f < 2; ++f) {
        bf16x8 kb = *(const bf16x8*)&Ks[cur][kr * 64 + (((f * 4 + g) ^ (kr & 7)) * 8)];
        z = mfma16(qf[f], kb, z);
      }
      s[n] = z;
    }

    // --- online softmax (row = 4g+i, spread over 16 lr-lanes)
    float corr[4], pvv[4][4];
#pragma unroll
    for (int i = 0; i < 4; ++i) {
      float tm = fmaxf(fmaxf(s[0][i], s[1][i]), fmaxf(s[2][i], s[3][i]));
#pragma unroll
      for (int ms = 1; ms < 16; ms <<= 1) tm = fmaxf(tm, __shfl_xor(tm, ms));
      float mn = fmaxf(mrow[i], tm);
      corr[i] = __expf(mrow[i] - mn);
      float rs = 0.f;
#pragma unroll
      for (int n = 0; n < 4; ++n) {
        float p = __expf(s[n][i] - mn);
        pvv[n][i] = p; rs += p;
      }
#pragma unroll
      for (int ms = 1; ms < 16; ms <<= 1) rs += __shfl_xor(rs, ms);
      lrowv[i] = lrowv[i] * corr[i] + rs;
      mrow[i] = mn;
    }
#pragma unroll
    for (int nd = 0; nd < 4; ++nd) {
      f32x4 o = oacc[nd];
      o[0] *= corr[0]; o[1] *= corr[1]; o[2] *= corr[2]; o[3] *= corr[3];
      oacc[nd] = o;
    }

    // --- P -> LDS (wave-local)
#pragma unroll
    for (int n = 0; n < 4; ++n)
#pragma unroll
      for (int i = 0; i < 4; ++i)
        Ps[wid][(4 * g + i) * 72 + n * 16 + lr] = f2bf(pvv[n][i]);
    asm volatile("s_waitcnt lgkmcnt(0)" ::: "memory");

    // --- PV: ctx[q][d] += P[q][k] V^T[d][k]
#pragma unroll
    for (int f = 0; f < 2; ++f) {
      bf16x8 pa = *(const bf16x8*)&Ps[wid][lr * 72 + f * 32 + 8 * g];
#pragma unroll
      for (int nd = 0; nd < 4; ++nd) {
        int dr = nd * 16 + lr;
        bf16x8 vb = *(const bf16x8*)&Vts[cur][dr * 64 + (((f * 4 + g) ^ (dr & 7)) * 8)];
        oacc[nd] = mfma16(pa, vb, oacc[nd]);
      }
    }
    __syncthreads();   // next tile landed (vmcnt0); reads of cur done (lgkm0)
    cur ^= 1;
  }

  // epilogue: ctx = oacc / l
  u16* Op = Ob + (size_t)bh * 65536 + (size_t)(qt * 128 + wid * 16) * 64;
#pragma unroll
  for (int nd = 0; nd < 4; ++nd)
#pragma unroll
    for (int i = 0; i < 4; ++i)
      Op[(4 * g + i) * 64 + nd * 16 + lr] = f2bf(oacc[nd][i] / lrowv[i]);
}

// ---------------- LayerNorm in-place over rows of out [4096][1024] ----------------
__global__ __launch_bounds__(256) void ln_kernel(
    float* __restrict__ out, const float* __restrict__ gamma, const float* __restrict__ beta)
{
  int row = blockIdx.x, tid = threadIdx.x;
  int lane = tid & 63, wid = tid >> 6;
  f32x4 v = *(const f32x4*)&out[(size_t)row * 1024 + tid * 4];
  float s = v[0] + v[1] + v[2] + v[3];
  float q = v[0] * v[0] + v[1] * v[1] + v[2] * v[2] + v[3] * v[3];
#pragma unroll
  for (int ms = 1; ms < 64; ms <<= 1) { s += __shfl_xor(s, ms); q += __shfl_xor(q, ms); }
  __shared__ float red[8];
  if (lane == 0) { red[wid] = s; red[wid + 4] = q; }
  __syncthreads();
  s = red[0] + red[1] + red[2] + red[3];
  q = red[4] + red[5] + red[6] + red[7];
  float mu = s * (1.f / 1024.f);
  float var = q * (1.f / 1024.f) - mu * mu;
  float inv = rsqrtf(var + 1e-5f);
  f32x4 g4 = *(const f32x4*)&gamma[tid * 4];
  f32x4 b4 = *(const f32x4*)&beta[tid * 4];
  f32x4 o;
#pragma unroll
  for (int j = 0; j < 4; ++j) o[j] = (v[j] - mu) * inv * g4[j] + b4[j];
  *(f32x4*)&out[(size_t)row * 1024 + tid * 4] = o;
}

// ---------------- launch ----------------
extern "C" void kernel_launch(void* const* d_in, const int* in_sizes, int n_in,
                              void* d_out, int out_size, void* d_ws, size_t ws_size,
                              hipStream_t stream) {
  const float* x     = (const float*)d_in[0];
  const float* Wq    = (const float*)d_in[1];
  const float* bq    = (const float*)d_in[2];
  const float* Wk    = (const float*)d_in[3];
  const float* bk    = (const float*)d_in[4];
  const float* Wv    = (const float*)d_in[5];
  const float* bv    = (const float*)d_in[6];
  const float* Wo    = (const float*)d_in[7];
  const float* bo    = (const float*)d_in[8];
  const float* gamma = (const float*)d_in[9];
  const float* beta  = (const float*)d_in[10];
  float* out = (float*)d_out;

  char* ws = (char*)d_ws;
  u16*   xb  = (u16*)ws;                                   // 8MB  [4096][1024] bf16 (reused as ctx)
  u16*   wb  = (u16*)(ws + (8u << 20));                    // 8MB  Wq|Wk|Wv|Wo bf16
  float* bc  = (float*)(ws + (16u << 20));                 // 12KB bq|bk|bv
  u16*   qkv = (u16*)(ws + (16u << 20) + 16384);           // 24MB Q | K | V^T bf16
  u16*   ctx = xb;                                         // overlay: xb dead after QKV GEMM

  prep_kernel<<<8195, 256, 0, stream>>>(x, Wq, Wk, Wv, Wo, bq, bk, bv, xb, wb, bc);

  dim3 g0(32, 24);
  gemm_bt<0><<<g0, 256, 0, stream>>>(xb, wb, bc, nullptr, qkv, nullptr);

  attn_kernel<<<512, 512, 0, stream>>>(qkv, qkv + 4194304, qkv + 8388608, ctx);

  dim3 g1(32, 8);
  gemm_bt<1><<<g1, 256, 0, stream>>>(ctx, wb + 3 * 1048576, bo, x, nullptr, out);

  ln_kernel<<<4096, 256, 0, stream>>>(out, gamma, beta);
}